// Round 6
// baseline (290.158 us; speedup 1.0000x reference)
//
#include <hip/hip_runtime.h>
#include <stdint.h>

typedef unsigned short u16;
typedef __bf16  bf16x8   __attribute__((ext_vector_type(8)));
typedef float   floatx4  __attribute__((ext_vector_type(4)));
typedef unsigned short ushortx4 __attribute__((ext_vector_type(4)));

__device__ __forceinline__ u16 f2bf(float f) {
  unsigned u = __builtin_bit_cast(unsigned, f);
  u += 0x7FFFu + ((u >> 16) & 1u);           // RNE; inputs are finite
  return (u16)(u >> 16);
}

#define GLD_LDS16(g, l)                                                        \
  __builtin_amdgcn_global_load_lds(                                            \
      (const __attribute__((address_space(1))) void*)(g),                      \
      (__attribute__((address_space(3))) void*)(l), 16, 0, 0)

#define VMW(N) asm volatile("s_waitcnt vmcnt(" #N ")" ::: "memory")

// ---------------------------------------------------------------------------
// Kernel 0a: weights fp32 -> bf16 (unchanged; verified).
// ---------------------------------------------------------------------------
__global__ __launch_bounds__(256) void cvt_w(
    const float* __restrict__ Wq, const float* __restrict__ Wk,
    const float* __restrict__ Wv, u16* __restrict__ dst)
{
  const int z = blockIdx.y;
  const float* src = (z == 0) ? Wq : (z == 1) ? Wk : Wv;
  u16* d = dst + (size_t)z * 262144;
  const int idx = (blockIdx.x * 256 + threadIdx.x) * 8;
  const float4 lo = *(const float4*)&src[idx];
  const float4 hi = *(const float4*)&src[idx + 4];
  union { u16 h[8]; uint4 v; } pk;
  pk.h[0] = f2bf(lo.x); pk.h[1] = f2bf(lo.y); pk.h[2] = f2bf(lo.z); pk.h[3] = f2bf(lo.w);
  pk.h[4] = f2bf(hi.x); pk.h[5] = f2bf(hi.y); pk.h[6] = f2bf(hi.z); pk.h[7] = f2bf(hi.w);
  *(uint4*)&d[idx] = pk.v;
}

// ---------------------------------------------------------------------------
// Kernel 0b: x fp32 -> bf16 (unchanged; verified).
// ---------------------------------------------------------------------------
__global__ __launch_bounds__(256) void cvt_x(
    const float* __restrict__ X, u16* __restrict__ dst)
{
  const int idx = (blockIdx.x * 256 + threadIdx.x) * 8;
  const float4 lo = *(const float4*)&X[idx];
  const float4 hi = *(const float4*)&X[idx + 4];
  union { u16 h[8]; uint4 v; } pk;
  pk.h[0] = f2bf(lo.x); pk.h[1] = f2bf(lo.y); pk.h[2] = f2bf(lo.z); pk.h[3] = f2bf(lo.w);
  pk.h[4] = f2bf(hi.x); pk.h[5] = f2bf(hi.y); pk.h[6] = f2bf(hi.z); pk.h[7] = f2bf(hi.w);
  *(uint4*)&dst[idx] = pk.v;
}

// ---------------------------------------------------------------------------
// Kernel 1: qkv8 — fused QKV projection on the 8-phase 256^2 skeleton.
// CHANGED (this round, all 3 MFMA kernels identically): removed the forced
// `s_waitcnt lgkmcnt(0)` + sched_barrier(0) between barrier #1 and the MFMA
// cluster.  That drain forced LDS-service (576 cyc/CU/phase) and the MFMA
// cluster (620 cyc) to run SERIALLY (measured 1870 cyc/phase vs m201's 825).
// Plain C++ ds_reads let the compiler insert counted per-operand lgkmcnt(N)
// so early MFMAs overlap the remaining LDS drain.  Correctness-neutral:
// all LDS producer/consumer protection (barriers, counted vmcnt, pre-barrier
// sched_barrier pinning) unchanged; only register-dep waits relaxed.
// ---------------------------------------------------------------------------
__global__ __launch_bounds__(512, 2) void qkv8(
    const u16* __restrict__ X16, const u16* __restrict__ Wb,
    u16* __restrict__ qo, u16* __restrict__ ko, u16* __restrict__ vto)
{
  __shared__ u16 lds[65536];                   // 128 KiB

  const int tid = threadIdx.x;
  const int w  = tid >> 6, l = tid & 63;
  const int lr = l & 15, lq = l >> 4;
  const int wA = (w & 1) * 16;                 // A(M) strip
  const int wB = (w >> 1) * 16;                // B(N) strip

  const int bx = blockIdx.x;                   // 0..383
  const int li = (bx & 7) * 48 + (bx >> 3);    // bijective XCD chunking
  const int z  = li >> 7, u = li & 127;        // 384 = 3*128

  const u16* Ag; const u16* Bg; u16* dst; float sc; size_t ostr; int mb, nb;
  if (z < 2) {
    Ag = Wb + (size_t)z * 262144; Bg = X16;
    dst = z ? ko : qo; sc = z ? 1.0f : 0.06375871732f; ostr = 512;
    mb = (u & 1) * 256;  nb = (u >> 1) * 256;  // M over 512 d, N over 16384 bs
  } else {
    Ag = X16; Bg = Wb + (size_t)2 * 262144;
    dst = vto; sc = 1.0f; ostr = 16384;
    mb = (u >> 1) * 256; nb = (u & 1) * 256;   // M over 16384 bs, N over 512 d
  }

  floatx4 acc[8][4];
  const floatx4 fz = {0.f, 0.f, 0.f, 0.f};
#pragma unroll
  for (int i = 0; i < 8; ++i)
#pragma unroll
    for (int j = 0; j < 4; ++j) acc[i][j] = fz;

  // stage half-tile s: kind 0=A-h0, 1=B-h0, 2=A-h1, 3=B-h1 of tile s>>2
  auto stage = [&](int s) {
    const int ts = s >> 2, kind = s & 3;
    const int mat = kind & 1, h = kind >> 1;
    const u16* src = mat ? Bg : Ag;
    const int rbase = mat ? nb : mb;
    u16* dstl = &lds[(ts & 1) * 32768 + mat * 16384];
#pragma unroll
    for (int i = 0; i < 2; ++i) {
      const int c = i * 512 + tid;             // 16B chunk within half
      const int r = h * 128 + (c >> 3), k16 = c & 7;
      const int k16s = k16 ^ (r & 7);          // inverse-swizzled source
      GLD_LDS16(src + (size_t)(rbase + r) * 512 + ts * 64 + k16s * 8,
                &dstl[r * 64 + k16 * 8]);
    }
  };

  // prologue: 6 half-tiles (tile0 complete + A0,B0 of tile1)
#pragma unroll
  for (int s = 0; s < 6; ++s) stage(s);
  VMW(4);                                      // tile0 resident
  __builtin_amdgcn_s_barrier();
  __builtin_amdgcn_sched_barrier(0);

  bf16x8 af[4][2];                             // current A-half (persists)
  bf16x8 bf0[2][2], bf1[2][2];                 // B-half0 / B-half1 (persist)

#pragma unroll
  for (int t = 0; t < 8; ++t) {
#pragma unroll
    for (int qd = 0; qd < 4; ++qd) {
      const int fmh = qd >> 1;
      const int fnh = fmh ^ (qd & 1);          // Gray: 00,01,11,10
      const u16* AB = &lds[(t & 1) * 32768];
      const u16* BB = AB + 16384;

      if (qd == 0 || qd == 2) {                // new A-half (8 reads)
#pragma unroll
        for (int im = 0; im < 4; ++im) {
          const int rA = (fmh * 4 + im) * 32 + wA + lr;
#pragma unroll
          for (int ks = 0; ks < 2; ++ks) {
            const int k16p = (ks * 4 + lq) ^ (rA & 7);
            af[im][ks] = *(const bf16x8*)&AB[rA * 64 + k16p * 8];
          }
        }
      }
      if (qd == 0) {                           // B-half0 (4 reads)
#pragma unroll
        for (int jn = 0; jn < 2; ++jn) {
          const int rB = jn * 64 + wB + lr;
#pragma unroll
          for (int ks = 0; ks < 2; ++ks) {
            const int k16p = (ks * 4 + lq) ^ (rB & 7);
            bf0[jn][ks] = *(const bf16x8*)&BB[rB * 64 + k16p * 8];
          }
        }
      }
      if (qd == 1) {                           // B-half1 (4 reads)
#pragma unroll
        for (int jn = 0; jn < 2; ++jn) {
          const int rB = (2 + jn) * 64 + wB + lr;
#pragma unroll
          for (int ks = 0; ks < 2; ++ks) {
            const int k16p = (ks * 4 + lq) ^ (rB & 7);
            bf1[jn][ks] = *(const bf16x8*)&BB[rB * 64 + k16p * 8];
          }
        }
      }

      const int s = t * 4 + qd + 6;
      if (s < 32) stage(s);

      __builtin_amdgcn_sched_barrier(0);
      __builtin_amdgcn_s_barrier();
      // (no lgkmcnt(0): compiler inserts counted lgkmcnt per MFMA operand,
      //  overlapping LDS drain with the MFMA cluster)

      __builtin_amdgcn_s_setprio(1);
      if (fnh) {
#pragma unroll
        for (int im = 0; im < 4; ++im)
#pragma unroll
          for (int jn = 0; jn < 2; ++jn)
#pragma unroll
            for (int ks = 0; ks < 2; ++ks)
              acc[fmh * 4 + im][2 + jn] =
                  __builtin_amdgcn_mfma_f32_16x16x32_bf16(
                      af[im][ks], bf1[jn][ks], acc[fmh * 4 + im][2 + jn], 0, 0, 0);
      } else {
#pragma unroll
        for (int im = 0; im < 4; ++im)
#pragma unroll
          for (int jn = 0; jn < 2; ++jn)
#pragma unroll
            for (int ks = 0; ks < 2; ++ks)
              acc[fmh * 4 + im][jn] =
                  __builtin_amdgcn_mfma_f32_16x16x32_bf16(
                      af[im][ks], bf0[jn][ks], acc[fmh * 4 + im][jn], 0, 0, 0);
      }
      __builtin_amdgcn_s_setprio(0);

      if (qd == 3) {
        if (t < 6)        VMW(4);
        else if (t == 6)  VMW(0);
      }
      __builtin_amdgcn_s_barrier();
      __builtin_amdgcn_sched_barrier(0);
    }
  }

  // ---- epilogue: 32 packed 8B stores, unified across z ----
  const int cr = lq * 4;
#pragma unroll
  for (int fm = 0; fm < 8; ++fm)
#pragma unroll
    for (int fn = 0; fn < 4; ++fn) {
      const int mv = mb + fm * 32 + wA + cr;
      const int nv = nb + fn * 64 + wB + lr;
      ushortx4 pk;
#pragma unroll
      for (int r = 0; r < 4; ++r) pk[r] = f2bf(acc[fm][fn][r] * sc);
      *(ushortx4*)&dst[(size_t)nv * ostr + mv] = pk;
    }
}

// ---------------------------------------------------------------------------
// Kernel 2: 8-phase 256^2 qk_exp8 (same lgkm-relaxation edit; otherwise the
// round-3/5 verified kernel).
// ---------------------------------------------------------------------------
__global__ __launch_bounds__(512, 2) void qk_exp8(
    const u16* __restrict__ q, const u16* __restrict__ k,
    u16* __restrict__ S, float* __restrict__ lsum)
{
  __shared__ u16 lds[65536];                   // 128 KiB

  const int tid = threadIdx.x;
  const int w  = tid >> 6, l = tid & 63;
  const int lr = l & 15, lq = l >> 4;
  const int wA = (w & 1) * 16;                 // A (key) strip
  const int wB = (w >> 1) * 16;                // B (qrow) strip
  const int kb0 = blockIdx.x * 256;            // key base
  const int qb0 = blockIdx.y * 256;            // qrow base
  const int b   = blockIdx.z;
  const size_t rb = (size_t)b * 4096;
  const u16* kg = k + rb * 512;
  const u16* qg = q + rb * 512;

  floatx4 acc[8][4];
  const floatx4 fz = {0.f, 0.f, 0.f, 0.f};
#pragma unroll
  for (int i = 0; i < 8; ++i)
#pragma unroll
    for (int j = 0; j < 4; ++j) acc[i][j] = fz;

  auto stage = [&](int s) {
    const int ts = s >> 2, kind = s & 3;
    const int mat = kind & 1, h = kind >> 1;   // mat: 0=A(k) 1=B(q)
    const u16* src = mat ? qg : kg;
    const int rbase = mat ? qb0 : kb0;
    u16* dst = &lds[(ts & 1) * 32768 + mat * 16384];
#pragma unroll
    for (int i = 0; i < 2; ++i) {
      const int c = i * 512 + tid;             // 16B chunk within half
      const int r = h * 128 + (c >> 3), k16 = c & 7;
      const int k16s = k16 ^ (r & 7);          // inverse-swizzled source
      GLD_LDS16(src + (size_t)(rbase + r) * 512 + ts * 64 + k16s * 8,
                &dst[r * 64 + k16 * 8]);
    }
  };

#pragma unroll
  for (int s = 0; s < 6; ++s) stage(s);
  VMW(4);                                      // tile0 resident
  __builtin_amdgcn_s_barrier();
  __builtin_amdgcn_sched_barrier(0);

  bf16x8 af[4][2];                             // current A-half (persists)
  bf16x8 bf0[2][2], bf1[2][2];                 // B-half0 / B-half1 (persist)

#pragma unroll
  for (int t = 0; t < 8; ++t) {
#pragma unroll
    for (int qd = 0; qd < 4; ++qd) {
      const int fmh = qd >> 1;
      const int fnh = fmh ^ (qd & 1);          // Gray: 00,01,11,10
      const u16* AB = &lds[(t & 1) * 32768];
      const u16* BB = AB + 16384;

      if (qd == 0 || qd == 2) {                // new A-half (8 reads)
#pragma unroll
        for (int im = 0; im < 4; ++im) {
          const int rA = (fmh * 4 + im) * 32 + wA + lr;
#pragma unroll
          for (int ks = 0; ks < 2; ++ks) {
            const int k16p = (ks * 4 + lq) ^ (rA & 7);
            af[im][ks] = *(const bf16x8*)&AB[rA * 64 + k16p * 8];
          }
        }
      }
      if (qd == 0) {                           // B-half0 (4 reads)
#pragma unroll
        for (int jn = 0; jn < 2; ++jn) {
          const int rB = jn * 64 + wB + lr;
#pragma unroll
          for (int ks = 0; ks < 2; ++ks) {
            const int k16p = (ks * 4 + lq) ^ (rB & 7);
            bf0[jn][ks] = *(const bf16x8*)&BB[rB * 64 + k16p * 8];
          }
        }
      }
      if (qd == 1) {                           // B-half1 (4 reads)
#pragma unroll
        for (int jn = 0; jn < 2; ++jn) {
          const int rB = (2 + jn) * 64 + wB + lr;
#pragma unroll
          for (int ks = 0; ks < 2; ++ks) {
            const int k16p = (ks * 4 + lq) ^ (rB & 7);
            bf1[jn][ks] = *(const bf16x8*)&BB[rB * 64 + k16p * 8];
          }
        }
      }

      const int s = t * 4 + qd + 6;
      if (s < 32) stage(s);

      __builtin_amdgcn_sched_barrier(0);
      __builtin_amdgcn_s_barrier();
      // (no lgkmcnt(0): compiler-managed counted waits)

      __builtin_amdgcn_s_setprio(1);
      if (fnh) {
#pragma unroll
        for (int im = 0; im < 4; ++im)
#pragma unroll
          for (int jn = 0; jn < 2; ++jn)
#pragma unroll
            for (int ks = 0; ks < 2; ++ks)
              acc[fmh * 4 + im][2 + jn] =
                  __builtin_amdgcn_mfma_f32_16x16x32_bf16(
                      af[im][ks], bf1[jn][ks], acc[fmh * 4 + im][2 + jn], 0, 0, 0);
      } else {
#pragma unroll
        for (int im = 0; im < 4; ++im)
#pragma unroll
          for (int jn = 0; jn < 2; ++jn)
#pragma unroll
            for (int ks = 0; ks < 2; ++ks)
              acc[fmh * 4 + im][jn] =
                  __builtin_amdgcn_mfma_f32_16x16x32_bf16(
                      af[im][ks], bf0[jn][ks], acc[fmh * 4 + im][jn], 0, 0, 0);
      }
      __builtin_amdgcn_s_setprio(0);

      if (qd == 3) {
        if (t < 6)        VMW(4);
        else if (t == 6)  VMW(0);
      }
      __builtin_amdgcn_s_barrier();
      __builtin_amdgcn_sched_barrier(0);
    }
  }

  const int cr = lq * 4;
  u16* Sb = S + ((size_t)b << 24);             // b * 4096 * 4096
  float js[4] = {0.f, 0.f, 0.f, 0.f};
#pragma unroll
  for (int fm = 0; fm < 8; ++fm)
#pragma unroll
    for (int fn = 0; fn < 4; ++fn) {
      const int key = kb0 + fm * 32 + wA + cr;
      const int qr  = qb0 + fn * 64 + wB + lr;
      ushortx4 pk;
      float s4 = 0.f;
#pragma unroll
      for (int r = 0; r < 4; ++r) {
        const float p = __builtin_amdgcn_exp2f(acc[fm][fn][r] - 17.31234049f);
        s4 += p;
        pk[r] = f2bf(p);
      }
      js[fn] += s4;
      *(ushortx4*)&Sb[(size_t)qr * 4096 + key] = pk;
    }
#pragma unroll
  for (int fn = 0; fn < 4; ++fn) {
    float s = js[fn];
    s += __shfl_xor(s, 16);                    // reduce over key-quads (lq)
    s += __shfl_xor(s, 32);
    if (lq == 0)
      atomicAdd(&lsum[rb + qb0 + fn * 64 + wB + lr], s);
  }
}

// ---------------------------------------------------------------------------
// Kernel 3: pv8 — 8-phase, BM=256/BN=128, K=4096 (same lgkm-relaxation edit).
// ---------------------------------------------------------------------------
#define PV_STG_A(TT, CK) do {                                                  \
    u16* dA_ = &lds[((TT) & 1) * 24576];                                       \
    _Pragma("unroll")                                                          \
    for (int i_ = 0; i_ < 2; ++i_) {                                           \
      const int c_ = i_ * 512 + tid, r_ = c_ >> 3, k_ = c_ & 7;                \
      GLD_LDS16(Sb + (size_t)(lm0 + (CK) * 128 + r_) * 4096 + (TT) * 64 +      \
                    (k_ ^ (r_ & 7)) * 8,                                       \
                &dA_[((CK) * 128 + r_) * 64 + k_ * 8]);                        \
    }                                                                          \
  } while (0)

#define PV_STG_B(TT) do {                                                      \
    u16* dB_ = &lds[((TT) & 1) * 24576 + 16384];                               \
    _Pragma("unroll")                                                          \
    for (int i_ = 0; i_ < 2; ++i_) {                                           \
      const int c_ = i_ * 512 + tid, r_ = c_ >> 3, k_ = c_ & 7;                \
      GLD_LDS16(vt + (size_t)(n0 + r_) * 16384 + bofs + (TT) * 64 +            \
                    (k_ ^ (r_ & 7)) * 8,                                       \
                &dB_[r_ * 64 + k_ * 8]);                                       \
    }                                                                          \
  } while (0)

#define PV_PH(T, PH, STAGE_CODE, TAIL_CODE) do {                               \
    const u16* AB_ = &lds[((T) & 1) * 24576];                                  \
    const u16* BB_ = AB_ + 16384;                                              \
    _Pragma("unroll")                                                          \
    for (int im_ = 0; im_ < 4; ++im_) {                                        \
      const int rA_ = ((PH) * 4 + im_) * 32 + wm16 + lr;                       \
      _Pragma("unroll")                                                        \
      for (int ks_ = 0; ks_ < 2; ++ks_) {                                      \
        const int kp_ = (ks_ * 4 + lq) ^ (rA_ & 7);                            \
        af[im_][ks_] = *(const bf16x8*)&AB_[rA_ * 64 + kp_ * 8];               \
      }                                                                        \
    }                                                                          \
    if ((PH) == 0) {                                                           \
      _Pragma("unroll")                                                        \
      for (int jn_ = 0; jn_ < 2; ++jn_) {                                      \
        const int rB_ = wn32 + jn_ * 16 + lr;                                  \
        _Pragma("unroll")                                                      \
        for (int ks_ = 0; ks_ < 2; ++ks_) {                                    \
          const int kp_ = (ks_ * 4 + lq) ^ (rB_ & 7);                          \
          bfv[jn_][ks_] = *(const bf16x8*)&BB_[rB_ * 64 + kp_ * 8];            \
        }                                                                      \
      }                                                                        \
    }                                                                          \
    STAGE_CODE;                                                                \
    __builtin_amdgcn_sched_barrier(0);                                         \
    __builtin_amdgcn_s_barrier();                                              \
    /* no lgkmcnt(0): compiler-managed counted waits */                        \
    __builtin_amdgcn_s_setprio(1);                                             \
    _Pragma("unroll")                                                          \
    for (int im_ = 0; im_ < 4; ++im_)                                          \
      _Pragma("unroll")                                                        \
      for (int jn_ = 0; jn_ < 2; ++jn_)                                        \
        _Pragma("unroll")                                                      \
        for (int ks_ = 0; ks_ < 2; ++ks_)                                      \
          acc[(PH) * 4 + im_][jn_] = __builtin_amdgcn_mfma_f32_16x16x32_bf16(  \
              af[im_][ks_], bfv[jn_][ks_], acc[(PH) * 4 + im_][jn_], 0, 0, 0); \
    __builtin_amdgcn_s_setprio(0);                                             \
    TAIL_CODE;                                                                 \
    __builtin_amdgcn_s_barrier();                                              \
    __builtin_amdgcn_sched_barrier(0);                                         \
  } while (0)

#define PV_TILE(T, G_A1, G_A0B, VMCODE) do {                                   \
    PV_PH(T, 0, { if (G_A1) PV_STG_A((T) + 1, 1); }, (void)0);                 \
    PV_PH(T, 1, { if (G_A0B) { PV_STG_A((T) + 2, 0); PV_STG_B((T) + 2); } },   \
          VMCODE);                                                             \
  } while (0)

__global__ __launch_bounds__(512, 2) void pv8(
    const u16* __restrict__ S, const u16* __restrict__ vt,
    const float* __restrict__ lsum, float* __restrict__ out)
{
  __shared__ u16 lds[49152];                   // 96 KiB

  const int tid = threadIdx.x;
  const int w  = tid >> 6, l = tid & 63;
  const int lr = l & 15, lq = l >> 4;
  const int wm16 = (w & 1) * 16;               // M strip within 32-row fm blk
  const int wn32 = (w >> 1) * 32;              // N strip (32 cols)

  const int wg = blockIdx.x;                   // 0..255
  const int li = (wg & 7) * 32 + (wg >> 3);    // bijective XCD-chunked
  const int n0 = (li & 3) * 128;               // d base
  const int m0 = (li >> 2) * 256;              // merged q-row base
  const int b  = m0 >> 12;
  const int lm0 = m0 & 4095;
  const u16* Sb = S + ((size_t)b << 24);
  const size_t bofs = (size_t)b * 4096;

  floatx4 acc[8][2];
  const floatx4 fz = {0.f, 0.f, 0.f, 0.f};
#pragma unroll
  for (int i = 0; i < 8; ++i) { acc[i][0] = fz; acc[i][1] = fz; }

  bf16x8 af[4][2], bfv[2][2];

  PV_STG_A(0, 0); PV_STG_B(0); PV_STG_A(0, 1); PV_STG_A(1, 0); PV_STG_B(1);
  VMW(4);
  __builtin_amdgcn_s_barrier();
  __builtin_amdgcn_sched_barrier(0);

  for (int t = 0; t < 62; t += 2) {
    PV_TILE(t,     1, 1, VMW(4));
    PV_TILE(t + 1, 1, 1, VMW(4));
  }
  PV_TILE(62, 1, 0, VMW(0));                   // stages A1(63); drain all
  PV_TILE(63, 0, 0, (void)0);

  const int cr = lq * 4;
#pragma unroll
  for (int fm = 0; fm < 8; ++fm) {
    const int m = m0 + fm * 32 + wm16 + cr;    // global merged q-row
    float inv[4];
#pragma unroll
    for (int r = 0; r < 4; ++r) inv[r] = 1.0f / lsum[m + r];
#pragma unroll
    for (int jn = 0; jn < 2; ++jn) {
      const int n = n0 + wn32 + jn * 16 + lr;
#pragma unroll
      for (int r = 0; r < 4; ++r)
        out[(size_t)(m + r) * 512 + n] = acc[fm][jn][r] * inv[r];
    }
  }
}

// ---------------------------------------------------------------------------
extern "C" void kernel_launch(void* const* d_in, const int* in_sizes, int n_in,
                              void* d_out, int out_size, void* d_ws, size_t ws_size,
                              hipStream_t stream) {
  (void)in_sizes; (void)n_in; (void)out_size; (void)ws_size;
  const float* x  = (const float*)d_in[0];
  const float* Wq = (const float*)d_in[1];
  const float* Wk = (const float*)d_in[2];
  const float* Wv = (const float*)d_in[3];
  float* out = (float*)d_out;
  u16* ws  = (u16*)d_ws;
  u16* qw  = ws;                                  // q row-major, 16 MB
  u16* kw  = qw + (size_t)16384 * 512;            // k row-major, 16 MB
  u16* vw  = kw + (size_t)16384 * 512;            // v^T [512][16384], 16 MB
  u16* x16 = vw + (size_t)16384 * 512;            // x bf16, 16 MB
  u16* wb  = x16 + (size_t)16384 * 512;           // weights bf16, 1.5 MB
  u16* Sp  = wb + (size_t)3 * 262144;             // P bf16 [4][4096][4096], 128 MB
  float* lsum = (float*)(Sp + ((size_t)4 << 24)); // [16384] fp32, 64 KB

  hipMemsetAsync(lsum, 0, 16384 * sizeof(float), stream);
  cvt_w<<<dim3(128, 3), dim3(256), 0, stream>>>(Wq, Wk, Wv, wb);
  cvt_x<<<dim3(4096), dim3(256), 0, stream>>>(x, x16);
  qkv8<<<dim3(384), dim3(512), 0, stream>>>(x16, wb, qw, kw, vw);
  qk_exp8<<<dim3(16, 16, 4), dim3(512), 0, stream>>>(qw, kw, Sp, lsum);
  pv8<<<dim3(256), dim3(512), 0, stream>>>(Sp, vw, lsum, out);
}